// Round 6
// baseline (182.022 us; speedup 1.0000x reference)
//
#include <hip/hip_runtime.h>
#include <cfloat>
#include <cmath>

#define BB 128
#define MM 50
#define AA 2100
#define NC 30
#define DCH 64
#define CHT 94                       // total channels = 64 + 30
#define GPB 525                      // 4-anchor groups per batch = AA/4
#define NITEM (NC * BB * GPB)        // 2,016,000 float4 work items
#define BLK 256
#define NBCE 1984                    // streaming BCE blocks
#define NBOX 64                      // box-scan blocks
#define NGRID (NBCE + NBOX)          // 2048 = 8 blocks/CU
#define NSLOT 64

// ws layout (memset region = first 1,076,480 bytes):
//   [0, 1075200)           mask: BB*AA u32 (bit c = class c, bit31 = fg)
//   [1075200, 1075712)     pcls: 64 f64 slots
//   [1075712, 1076224)     pbox: 64 f64 slots
//   [1076224, 1076480)     pcnt: 64 u32 slots
#define MASK_BYTES (BB * AA * 4)

// One wave per (b,m): argmin over 2100 anchors (squared dist, argmin-equal),
// tie-break lowest index (jnp.argmin), scatter class-bit + fg-bit via atomicOr.
__global__ void assign_kernel(const float* __restrict__ txy,
                              const int* __restrict__ tcls,
                              const unsigned char* __restrict__ valid,
                              const float* __restrict__ anchors,
                              unsigned int* __restrict__ mask) {
    int gtid = blockIdx.x * blockDim.x + threadIdx.x;
    int pair = gtid >> 6;
    int lane = gtid & 63;
    if (pair >= BB * MM) return;
    if (!valid[pair]) return;          // invalid scatters nothing (max with 0)

    float cx = txy[pair * 2 + 0] * 320.0f;
    float cy = txy[pair * 2 + 1] * 320.0f;

    const float2* __restrict__ anc = (const float2*)anchors;
    float bd = FLT_MAX;
    int   bi = 0x7fffffff;
    #pragma unroll 8
    for (int a = lane; a < AA; a += 64) {
        float2 p = anc[a];
        float dx = p.x - cx;
        float dy = p.y - cy;
        float d = dx * dx + dy * dy;
        if (d < bd) { bd = d; bi = a; }          // strict < keeps lowest index
    }
    for (int off = 32; off > 0; off >>= 1) {     // tie-break lowest index
        float od = __shfl_xor(bd, off);
        int   oi = __shfl_xor(bi, off);
        if (od < bd || (od == bd && oi < bi)) { bd = od; bi = oi; }
    }
    if (lane == 0) {
        int b = pair / MM;
        atomicOr(&mask[b * AA + bi], (1u << tcls[pair]) | 0x80000000u);
    }
}

// Streaming loss. BCE blocks: one float4 of one class channel per item,
// mask as uint4 (L2-hot, re-read 30x). Box blocks: scan mask words, fg hits
// sum 64 dist channels; cnt = # fg words (dedup'd by construction).
__global__ __launch_bounds__(BLK)
void loss_kernel(const float* __restrict__ pred,
                 const unsigned int* __restrict__ mask,
                 double* __restrict__ pcls,
                 double* __restrict__ pbox,
                 unsigned int* __restrict__ pcnt) {
    float acc = 0.0f;          // cls partial
    float box = 0.0f;          // box partial
    unsigned int nfg = 0;

    if (blockIdx.x < NBCE) {
        int tid = blockIdx.x * BLK + threadIdx.x;
        const int stride = NBCE * BLK;                    // 507,904
        for (int item = tid; item < NITEM; item += stride) {
            int c = item / (BB * GPB);
            int r = item - c * (BB * GPB);
            int b = r / GPB;
            int g = r - b * GPB;
            float4 v  = *(const float4*)(pred + (size_t)(b * CHT + DCH + c) * AA + g * 4);
            uint4  mw = *(const uint4*)(mask + b * AA + g * 4);
            float sp;
            // BCE = softplus(x) - t*x, t in {0,1}
            sp = fmaxf(v.x, 0.f) + __logf(1.f + __expf(-fabsf(v.x)));
            acc += sp - (((mw.x >> c) & 1u) ? v.x : 0.f);
            sp = fmaxf(v.y, 0.f) + __logf(1.f + __expf(-fabsf(v.y)));
            acc += sp - (((mw.y >> c) & 1u) ? v.y : 0.f);
            sp = fmaxf(v.z, 0.f) + __logf(1.f + __expf(-fabsf(v.z)));
            acc += sp - (((mw.z >> c) & 1u) ? v.z : 0.f);
            sp = fmaxf(v.w, 0.f) + __logf(1.f + __expf(-fabsf(v.w)));
            acc += sp - (((mw.w >> c) & 1u) ? v.w : 0.f);
        }
    } else {
        int tid = (blockIdx.x - NBCE) * BLK + threadIdx.x;
        const int stride = NBOX * BLK;                    // 16,384
        for (int i = tid; i < BB * AA; i += stride) {
            unsigned int mw = mask[i];
            if (mw >> 31) {
                int b = i / AA;
                int a = i - b * AA;
                const float* __restrict__ pd = pred + (size_t)b * CHT * AA + a;
                float s = 0.0f;
                #pragma unroll 16
                for (int ch = 0; ch < DCH; ++ch) s += pd[(size_t)ch * AA];
                float e = s * (1.0f / 64.0f) - 1.0f;
                float ae = fabsf(e);
                box += (ae <= 1.0f) ? 0.5f * e * e : ae - 0.5f;
                nfg++;
            }
        }
    }

    // wave reduce
    for (int off = 32; off > 0; off >>= 1) {
        acc += __shfl_down(acc, off);
        box += __shfl_down(box, off);
        nfg += __shfl_down(nfg, off);
    }
    __shared__ float s_cls[4];
    __shared__ float s_box[4];
    __shared__ unsigned int s_fg[4];
    int lane = threadIdx.x & 63;
    int w    = threadIdx.x >> 6;
    if (lane == 0) { s_cls[w] = acc; s_box[w] = box; s_fg[w] = nfg; }
    __syncthreads();
    if (threadIdx.x == 0) {
        int slot = blockIdx.x & (NSLOT - 1);
        float tc = s_cls[0] + s_cls[1] + s_cls[2] + s_cls[3];
        float tb = s_box[0] + s_box[1] + s_box[2] + s_box[3];
        unsigned int tf = s_fg[0] + s_fg[1] + s_fg[2] + s_fg[3];
        atomicAdd(&pcls[slot], (double)tc);
        if (tb != 0.0f) atomicAdd(&pbox[slot], (double)tb);
        if (tf)         atomicAdd(&pcnt[slot], tf);
    }
}

__global__ void finalize_kernel(const double* __restrict__ pcls,
                                const double* __restrict__ pbox,
                                const unsigned int* __restrict__ pcnt,
                                float* __restrict__ out) {
    int t = threadIdx.x;               // 64 threads = 1 wave
    double cs = pcls[t];
    double bs = pbox[t];
    unsigned int ct = pcnt[t];
    for (int off = 32; off > 0; off >>= 1) {
        cs += __shfl_down(cs, off);
        bs += __shfl_down(bs, off);
        ct += __shfl_down(ct, off);
    }
    if (t == 0) {
        out[0] = (ct > 0) ? (float)(bs / (double)ct) : 0.0f;       // loss_box
        out[1] = (float)(cs / (double)((size_t)BB * NC * AA));     // loss_cls
    }
}

extern "C" void kernel_launch(void* const* d_in, const int* in_sizes, int n_in,
                              void* d_out, int out_size, void* d_ws, size_t ws_size,
                              hipStream_t stream) {
    const float*         pred    = (const float*)d_in[0];
    const int*           tcls    = (const int*)d_in[1];
    const float*         txy     = (const float*)d_in[2];
    const unsigned char* valid   = (const unsigned char*)d_in[3];  // numpy bool
    const float*         anchors = (const float*)d_in[4];
    float* out = (float*)d_out;

    unsigned int* mask = (unsigned int*)d_ws;
    double*       pcls = (double*)((char*)d_ws + MASK_BYTES);
    double*       pbox = (double*)((char*)d_ws + MASK_BYTES + 512);
    unsigned int* pcnt = (unsigned int*)((char*)d_ws + MASK_BYTES + 1024);

    // zero mask + slots (~1 MB, ~0.2 us)
    hipMemsetAsync(d_ws, 0, MASK_BYTES + 1280, stream);

    {   // assignment: one wave per (b,m)
        int threads = BB * MM * 64;
        int grid = (threads + BLK - 1) / BLK;
        assign_kernel<<<grid, BLK, 0, stream>>>(txy, tcls, valid, anchors, mask);
    }
    loss_kernel<<<NGRID, BLK, 0, stream>>>(pred, mask, pcls, pbox, pcnt);
    finalize_kernel<<<1, 64, 0, stream>>>(pcls, pbox, pcnt, out);
}